// Round 19
// baseline (131.888 us; speedup 1.0000x reference)
//
#include <hip/hip_runtime.h>
#include <hip/hip_bf16.h>

typedef short v8s __attribute__((ext_vector_type(8)));
typedef float v4f __attribute__((ext_vector_type(4)));

// ---------------- kernel A: MLP (high-register, LDS-resident weights) ------
#define A_THREADS 1024   // 16 waves x 16 rows x 4 tiles = 1024 rows/block
#define A_WAVES   16
#define A_NTILES  4
#define A_ROWS    1024
// d_ws frag order: W1 0-48, W2 49-76, W3 77-92 (slot s at LDS s*1024)
#define W1F     0
#define W2F     49
#define W3F     77
#define SLABB   95232                    // 93 frag slots end here
#define SLAB_STRIDE 260                  // 65 dwords: bank +1/row, low conflict
#define SLAB_SIZE   4160                 // 16 rows * 260
#define LDS_TOTAL   (SLABB + A_WAVES * SLAB_SIZE)   // 161,792 <= 160 KiB

__device__ __forceinline__ unsigned short f2bf(float f) {
    union { __hip_bfloat16 h; unsigned short u; } c;
    c.h = __float2bfloat16(f);
    return c.u;
}
__device__ __forceinline__ unsigned pk2(float a, float b) {
    return (unsigned)f2bf(a) | ((unsigned)f2bf(b) << 16);
}
__device__ __forceinline__ v4f mfma16(v8s a, v8s b, v4f c) {
    return __builtin_amdgcn_mfma_f32_16x16x32_bf16(a, b, c, 0, 0, 0);
}
__device__ __forceinline__ v8s mkfrag(float4 a, float4 b) {
    union { unsigned u[4]; v8s s; } t;
    t.u[0] = pk2(a.x, a.y); t.u[1] = pk2(a.z, a.w);
    t.u[2] = pk2(b.x, b.y); t.u[3] = pk2(b.z, b.w);
    return t.s;
}
__device__ __forceinline__ void gload_lds16(const void* g, void* l) {
    __builtin_amdgcn_global_load_lds(
        (const __attribute__((address_space(1))) void*)g,
        (__attribute__((address_space(3))) void*)l, 16, 0, 0);
}

// ---- prep: weights -> MFMA B-fragment layout (bf16, zero-padded) ----------
// frag(nt,kc): lane l holds B[k = kc*32+(l>>4)*8+j][n = nt*16+(l&15)], j=0..7
__global__ void prep_weights(const float* __restrict__ W1,
                             const float* __restrict__ W2,
                             const float* __restrict__ W3,
                             uint4* __restrict__ wf) {
    const int bid = blockIdx.x, l = threadIdx.x;
    const float* W; int K, N, KC, base, f;
    if (bid < 49)      { W = W1; K = 200; N = 100; KC = 7; base = W1F * 64; f = bid; }
    else if (bid < 77) { W = W2; K = 100; N = 100; KC = 4; base = W2F * 64; f = bid - 49; }
    else               { W = W3; K = 100; N = 64;  KC = 4; base = W3F * 64; f = bid - 77; }
    const int kc = f % KC;
    const int n  = (f / KC) * 16 + (l & 15);
    unsigned u[4];
    #pragma unroll
    for (int p = 0; p < 4; ++p) {
        const int k0 = kc * 32 + (l >> 4) * 8 + p * 2;
        const float a = (k0     < K && n < N) ? W[(size_t)k0 * N + n]       : 0.f;
        const float b = (k0 + 1 < K && n < N) ? W[(size_t)(k0 + 1) * N + n] : 0.f;
        u[p] = pk2(a, b);
    }
    wf[base + f * 64 + l] = make_uint4(u[0], u[1], u[2], u[3]);
}

__global__ __launch_bounds__(A_THREADS, 4)   // 128-reg cap; lean body ~105 regs
void ar_mlp(const float* __restrict__ x,
            const float* __restrict__ b1, const float* __restrict__ b2,
            const float* __restrict__ b3,
            const uint4* __restrict__ wf,
            float* __restrict__ dp)          // DP output = d_out (f32)
{
    extern __shared__ __align__(16) unsigned char L[];
    const int tid  = threadIdx.x;
    const int lane = tid & 63;
    const int wid  = tid >> 6;
    const int l15  = lane & 15;
    const int l4   = lane >> 4;
    const int blk  = blockIdx.x;

#define XLOAD(d0, d1, base_row, kk)                                     \
    { int kb = (kk) * 32 + l4 * 8;                                      \
      kb = (kb + 8 <= 200) ? kb : 168;   /* clamp x zero-pad W1 = 0 */  \
      const float* p_ = x + ((base_row) + l15) * 200;                   \
      d0 = *(const float4*)(p_ + kb);                                   \
      d1 = *(const float4*)(p_ + kb + 4); }

    // wave rows: [gw0, gw0+64), tile t rows gw0 + t*16
    const size_t gw0 = (size_t)blk * A_ROWS + (size_t)wid * 64;

    // rolling 3-chunk X window (24 VGPR)
    float4 xv[3][2];
    XLOAD(xv[0][0], xv[0][1], gw0, 0);
    XLOAD(xv[1][0], xv[1][1], gw0, 1);
    XLOAD(xv[2][0], xv[2][1], gw0, 2);

    // one-time stage: all 93 frags -> LDS
    for (int s = wid; s < 93; s += A_WAVES)
        gload_lds16(wf + s * 64 + lane, L + s * 1024);
    __syncthreads();   // THE only barrier: X window in flight/regs, frags in

#define FRAG_W1(f)  (*(const uint4*)(&L[(W1F + (f)) * 1024 + lane * 16]))
#define FRAG_W2(f)  (*(const uint4*)(&L[(W2F + (f)) * 1024 + lane * 16]))
#define FRAG_W3(f)  (*(const uint4*)(&L[(W3F + (f)) * 1024 + lane * 16]))

    // affine slab bases (ds offsets compile-time)
    const int sb      = SLABB + wid * SLAB_SIZE;
    const int sb_epi  = sb + (l4 * 4) * SLAB_STRIDE + l15 * 2;  // +r*260+nt*32
    const int sb_rd   = sb + l15 * SLAB_STRIDE + l4 * 16;       // +kc*64

    #pragma unroll 1
    for (int t = 0; t < A_NTILES; ++t) {
        const size_t gw = gw0 + t * 16;

        // ================= layer 1: h1 = relu(X @ W1 + b1) ==============
        v4f acc[7];
        #pragma unroll
        for (int nt = 0; nt < 7; ++nt) acc[nt] = (v4f){0.f, 0.f, 0.f, 0.f};
        #pragma unroll
        for (int kc = 0; kc < 7; ++kc) {
            uint4 bu[7];
            #pragma unroll
            for (int nt = 0; nt < 7; ++nt) bu[nt] = FRAG_W1(nt * 7 + kc);
            const v8s af = mkfrag(xv[kc % 3][0], xv[kc % 3][1]);
            if (kc < 4) XLOAD(xv[kc % 3][0], xv[kc % 3][1], gw, kc + 3);
            #pragma unroll
            for (int nt = 0; nt < 7; ++nt)
                acc[nt] = mfma16(af, *(const v8s*)&bu[nt], acc[nt]);
        }
        // next tile's first window chunks stream in under epi/L2/L3
        if (t < A_NTILES - 1) {
            XLOAD(xv[0][0], xv[0][1], gw + 16, 0);
            XLOAD(xv[1][0], xv[1][1], gw + 16, 1);
            XLOAD(xv[2][0], xv[2][1], gw + 16, 2);
        }

        // epilogue -> slab (bf16 [16 rows][stride 260]); transient bias
        {
            float bv[7];
            #pragma unroll
            for (int nt = 0; nt < 7; ++nt) {
                const int c = nt * 16 + l15;
                bv[nt] = (c < 100) ? b1[c] : 0.f;
            }
            #pragma unroll
            for (int nt = 0; nt < 7; ++nt)
                #pragma unroll
                for (int r = 0; r < 4; ++r) {
                    const float v = fmaxf(acc[nt][r] + bv[nt], 0.f);
                    *(unsigned short*)(&L[sb_epi + r * SLAB_STRIDE + nt * 32]) =
                        f2bf(v);
                }
        }
        // zero cols 112..127 (100..111 zero via zero-padded frags)
        if (lane < 32)
            *(uint4*)(&L[sb + (lane >> 1) * SLAB_STRIDE + 224 + (lane & 1) * 16]) =
                make_uint4(0, 0, 0, 0);

        // ================= layer 2: h2 = relu(h1 @ W2 + b2) =============
        v4f acc2[7];
        #pragma unroll
        for (int nt = 0; nt < 7; ++nt) acc2[nt] = (v4f){0.f, 0.f, 0.f, 0.f};
        #pragma unroll
        for (int kc = 0; kc < 4; ++kc) {
            uint4 bu[7];
            #pragma unroll
            for (int nt = 0; nt < 7; ++nt) bu[nt] = FRAG_W2(nt * 4 + kc);
            uint4 t0 = *(const uint4*)(&L[sb_rd + kc * 64]);
            const v8s af = *(v8s*)&t0;
            #pragma unroll
            for (int nt = 0; nt < 7; ++nt)
                acc2[nt] = mfma16(af, *(const v8s*)&bu[nt], acc2[nt]);
        }
        {
            float bv[7];
            #pragma unroll
            for (int nt = 0; nt < 7; ++nt) {
                const int c = nt * 16 + l15;
                bv[nt] = (c < 100) ? b2[c] : 0.f;
            }
            #pragma unroll
            for (int nt = 0; nt < 7; ++nt)
                #pragma unroll
                for (int r = 0; r < 4; ++r) {
                    const float v = fmaxf(acc2[nt][r] + bv[nt], 0.f);
                    *(unsigned short*)(&L[sb_epi + r * SLAB_STRIDE + nt * 32]) =
                        f2bf(v);
                }
        }

        // ================= layer 3: DP = h2 @ W3 + b3 -> GLOBAL =========
        v4f acc3[4];
        #pragma unroll
        for (int nt = 0; nt < 4; ++nt) acc3[nt] = (v4f){0.f, 0.f, 0.f, 0.f};
        #pragma unroll
        for (int kc = 0; kc < 4; ++kc) {
            uint4 bu[4];
            #pragma unroll
            for (int nt = 0; nt < 4; ++nt) bu[nt] = FRAG_W3(nt * 4 + kc);
            uint4 t0 = *(const uint4*)(&L[sb_rd + kc * 64]);
            const v8s af = *(v8s*)&t0;
            #pragma unroll
            for (int nt = 0; nt < 4; ++nt)
                acc3[nt] = mfma16(af, *(const v8s*)&bu[nt], acc3[nt]);
        }
        {
            float bv[4];
            #pragma unroll
            for (int nt = 0; nt < 4; ++nt) bv[nt] = b3[nt * 16 + l15];
            // direct store: per (nt,r) 64 lanes -> 4 x 64B segments
            #pragma unroll
            for (int nt = 0; nt < 4; ++nt)
                #pragma unroll
                for (int r = 0; r < 4; ++r)
                    dp[(gw + l4 * 4 + r) * 64 + nt * 16 + l15] =
                        acc3[nt][r] + bv[nt];
        }
    }
#undef FRAG_W1
#undef FRAG_W2
#undef FRAG_W3
#undef XLOAD
}

// ---------------- kernel B: GAS recurrence (high-occupancy streaming) ------
__global__ void ar_gas_scan(float* __restrict__ io,     // d_out: DP in, out out
                            const float* __restrict__ last_mu,
                            const float* __restrict__ last_sigma,
                            const float* __restrict__ p_amu,
                            const float* __restrict__ p_as,
                            const float* __restrict__ p_bmu,
                            const float* __restrict__ p_bs,
                            const float* __restrict__ p_omu,
                            const float* __restrict__ p_os,
                            const float* __restrict__ p_nu,
                            const float* __restrict__ p_ns)
{
    const int row = blockIdx.x * 256 + threadIdx.x;   // 262144 threads
    float4* rp = (float4*)(io + (size_t)row * 64);    // own row, in-place

    const float anu = *p_nu,  ans = *p_ns;
    const float aMu = *p_amu, aSg = *p_as;
    const float bMu = *p_bmu, bSg = *p_bs;
    const float oMu = *p_omu, oSg = *p_os;
    const float w   = 1.f + __builtin_amdgcn_rcpf(anu);
    const float cmu = ans * aMu * w;
    const float cs  = ans * aSg * w;
    const float bs2 = bSg - ans * aSg;

    float mu = last_mu[row];
    float s2 = last_sigma[row];

    float4 c[16];
    c[0] = rp[0]; c[1] = rp[1];          // 2-deep rolling prefetch

#define GAS_STEP(Y, O)                                                  \
    {   const float e    = (Y) - mu;                                    \
        const float nus2 = anu * s2;                                    \
        const float den  = fmaf(e, e, nus2);                            \
        const float r0   = __builtin_amdgcn_rcpf(den);                  \
        const float p    = e * nus2 * r0;                               \
        mu = fmaf(cmu, p, fmaf(bMu, mu, oMu));                          \
        s2 = fmaf(cs, e * p, fmaf(bs2, s2, oSg));                       \
        (O) = fmaf((Y), __builtin_amdgcn_sqrtf(s2), mu); }

    #pragma unroll
    for (int q = 0; q < 16; ++q) {
        if (q + 2 < 16) c[q + 2] = rp[q + 2];         // read ahead of write
        float4 d = c[q];
        float o0, o1, o2, o3;
        GAS_STEP(d.x, o0); GAS_STEP(d.y, o1);
        GAS_STEP(d.z, o2); GAS_STEP(d.w, o3);
        rp[q] = make_float4(o0, o1, o2, o3);
    }
#undef GAS_STEP
}

extern "C" void kernel_launch(void* const* d_in, const int* in_sizes, int n_in,
                              void* d_out, int out_size, void* d_ws, size_t ws_size,
                              hipStream_t stream) {
    const float* x          = (const float*)d_in[0];
    const float* last_mu    = (const float*)d_in[1];
    const float* last_sigma = (const float*)d_in[2];
    const float* amu        = (const float*)d_in[3];
    const float* asig       = (const float*)d_in[4];
    const float* bmu        = (const float*)d_in[5];
    const float* bsig       = (const float*)d_in[6];
    const float* omu        = (const float*)d_in[7];
    const float* osig       = (const float*)d_in[8];
    const float* nu         = (const float*)d_in[9];
    const float* ns         = (const float*)d_in[10];
    const float* W1         = (const float*)d_in[11];
    const float* b1         = (const float*)d_in[12];
    const float* W2         = (const float*)d_in[13];
    const float* b2         = (const float*)d_in[14];
    const float* W3         = (const float*)d_in[15];
    const float* b3         = (const float*)d_in[16];
    float* out = (float*)d_out;

    uint4* wf = (uint4*)d_ws;   // 95,232 B fragment table (93 frags)
    prep_weights<<<93, 64, 0, stream>>>(W1, W2, W3, wf);

    hipFuncSetAttribute((const void*)ar_mlp,
                        hipFuncAttributeMaxDynamicSharedMemorySize, LDS_TOTAL);

    const int B = in_sizes[1];                 // 262144
    // A: MLP -> DP written into d_out (f32, exactly out_size elements)
    ar_mlp<<<dim3(B / A_ROWS), dim3(A_THREADS), LDS_TOTAL, stream>>>(
        x, b1, b2, b3, wf, out);
    // B: GAS recurrence transforms d_out in place at full occupancy
    ar_gas_scan<<<dim3(B / 256), dim3(256), 0, stream>>>(
        out, last_mu, last_sigma,
        amu, asig, bmu, bsig, omu, osig, nu, ns);
}

// Round 20
// 107.016 us; speedup vs baseline: 1.2324x; 1.2324x over previous
//
#include <hip/hip_runtime.h>
#include <hip/hip_bf16.h>

typedef short v8s __attribute__((ext_vector_type(8)));
typedef float v4f __attribute__((ext_vector_type(4)));

#define THREADS 768      // 12 waves -> 3 waves/SIMD (reg cap 170; body ~116)
#define WAVES   12
#define NTILES  4        // per wave: 4 tiles x 16 rows = 64 rows
#define WTASKS  4096     // 262144 / 64 rows per wave-task
// d_ws frag order: W1 0-48, W2 49-76, W3 77-92 (slot s at LDS s*1024)
#define W1F     0
#define W2F     49
#define W3F     77
#define SLABB   95232                    // 93 frag slots end here
#define SLAB_STRIDE 264                  // bank += 2 per row -> low conflict
#define SLAB_SIZE   4224                 // 16 rows * 264
#define LDS_TOTAL   (SLABB + WAVES * SLAB_SIZE)   // 145,920 B -> 1 block/CU

__device__ __forceinline__ unsigned short f2bf(float f) {
    union { __hip_bfloat16 h; unsigned short u; } c;
    c.h = __float2bfloat16(f);
    return c.u;
}
__device__ __forceinline__ unsigned pk2(float a, float b) {
    return (unsigned)f2bf(a) | ((unsigned)f2bf(b) << 16);
}
__device__ __forceinline__ v4f mfma16(v8s a, v8s b, v4f c) {
    return __builtin_amdgcn_mfma_f32_16x16x32_bf16(a, b, c, 0, 0, 0);
}
__device__ __forceinline__ v8s mkfrag(float4 a, float4 b) {
    union { unsigned u[4]; v8s s; } t;
    t.u[0] = pk2(a.x, a.y); t.u[1] = pk2(a.z, a.w);
    t.u[2] = pk2(b.x, b.y); t.u[3] = pk2(b.z, b.w);
    return t.s;
}
__device__ __forceinline__ void gload_lds16(const void* g, void* l) {
    __builtin_amdgcn_global_load_lds(
        (const __attribute__((address_space(1))) void*)g,
        (__attribute__((address_space(3))) void*)l, 16, 0, 0);
}

// ---- prep: weights -> MFMA B-fragment layout (bf16, zero-padded) ----------
// frag(nt,kc): lane l holds B[k = kc*32+(l>>4)*8+j][n = nt*16+(l&15)], j=0..7
__global__ void prep_weights(const float* __restrict__ W1,
                             const float* __restrict__ W2,
                             const float* __restrict__ W3,
                             uint4* __restrict__ wf) {
    const int bid = blockIdx.x, l = threadIdx.x;
    const float* W; int K, N, KC, base, f;
    if (bid < 49)      { W = W1; K = 200; N = 100; KC = 7; base = W1F * 64; f = bid; }
    else if (bid < 77) { W = W2; K = 100; N = 100; KC = 4; base = W2F * 64; f = bid - 49; }
    else               { W = W3; K = 100; N = 64;  KC = 4; base = W3F * 64; f = bid - 77; }
    const int kc = f % KC;
    const int n  = (f / KC) * 16 + (l & 15);
    unsigned u[4];
    #pragma unroll
    for (int p = 0; p < 4; ++p) {
        const int k0 = kc * 32 + (l >> 4) * 8 + p * 2;
        const float a = (k0     < K && n < N) ? W[(size_t)k0 * N + n]       : 0.f;
        const float b = (k0 + 1 < K && n < N) ? W[(size_t)(k0 + 1) * N + n] : 0.f;
        u[p] = pk2(a, b);
    }
    wf[base + f * 64 + l] = make_uint4(u[0], u[1], u[2], u[3]);
}

__global__ __launch_bounds__(THREADS, 3)   // 3 waves/EU -> cap 170; body ~116
void ar_gas_v20(const float* __restrict__ x,
                const float* __restrict__ last_mu,
                const float* __restrict__ last_sigma,
                const float* __restrict__ p_amu, const float* __restrict__ p_as,
                const float* __restrict__ p_bmu, const float* __restrict__ p_bs,
                const float* __restrict__ p_omu, const float* __restrict__ p_os,
                const float* __restrict__ p_nu,  const float* __restrict__ p_ns,
                const float* __restrict__ b1, const float* __restrict__ b2,
                const float* __restrict__ b3,
                const uint4* __restrict__ wf,
                float* __restrict__ out)
{
    extern __shared__ __align__(16) unsigned char L[];
    const int tid  = threadIdx.x;
    const int lane = tid & 63;
    const int wid  = tid >> 6;
    const int l15  = lane & 15;
    const int l4   = lane >> 4;

    // wave-task id; tail waves (>= WTASKS) compute garbage on row 0, skip stores
    const int  wgid   = blockIdx.x * WAVES + wid;
    const bool active = (wgid < WTASKS);
    const size_t gw0  = active ? (size_t)wgid * 64 : 0;

    // GAS scalars (uniform)
    const float anu = *p_nu,  ans = *p_ns;
    const float aMu = *p_amu, aSg = *p_as;
    const float bMu = *p_bmu, bSg = *p_bs;
    const float oMu = *p_omu, oSg = *p_os;
    const float wS  = 1.f + __builtin_amdgcn_rcpf(anu);
    const float cmu = ans * aMu * wS;
    const float cs  = ans * aSg * wS;
    const float bs2 = bSg - ans * aSg;

#define XLOADT(dst, base_row, kk)                                       \
    { int kb = (kk) * 32 + l4 * 8;                                      \
      kb = (kb + 8 <= 200) ? kb : 168;   /* clamp x zero-pad W1 = 0 */  \
      const float* p_ = x + ((base_row) + l15) * 200;                   \
      dst[kk][0] = *(const float4*)(p_ + kb);                           \
      dst[kk][1] = *(const float4*)(p_ + kb + 4); }

    // ---- prologue burst: X(tile0) into 56 VGPRs + all 93 frags -> LDS ----
    float4 xv[7][2];
    #pragma unroll
    for (int kc = 0; kc < 7; ++kc) XLOADT(xv, gw0, kc);

    for (int s = wid; s < 93; s += WAVES)
        gload_lds16(wf + s * 64 + lane, L + s * 1024);
    __syncthreads();   // THE only barrier: X in regs, all frags resident

#define FRAG_W1(f)  (*(const uint4*)(&L[(W1F + (f)) * 1024 + lane * 16]))
#define FRAG_W2(f)  (*(const uint4*)(&L[(W2F + (f)) * 1024 + lane * 16]))
#define FRAG_W3(f)  (*(const uint4*)(&L[(W3F + (f)) * 1024 + lane * 16]))

    // affine slab bases (all ds offsets are compile-time constants)
    const int sb      = SLABB + wid * SLAB_SIZE;
    const int sb_epi  = sb + (l4 * 4) * SLAB_STRIDE + l15 * 2;  // +r*264+nt*32
    const int sb_rd   = sb + l15 * SLAB_STRIDE + l4 * 16;       // +kc*64
    const int sb_dpw  = sb + (l4 * 4) * SLAB_STRIDE + l15 * 4;  // +r*264+nt*64
    const int sb_gas  = sb + l15 * SLAB_STRIDE;                 // +q*16
    const int sb_st   = sb + l4 * SLAB_STRIDE + l15 * 16;       // +i*1056

    #pragma unroll 1
    for (int t = 0; t < NTILES; ++t) {
        const size_t gw = gw0 + t * 16;

        // state loads now; consumed at GAS ~6K cyc later
        const float mu_init = last_mu[gw + l15];
        const float s2_init = last_sigma[gw + l15];

        // ================= layer 1: h1 = relu(X @ W1 + b1) ==============
        v4f acc[7];
        #pragma unroll
        for (int nt = 0; nt < 7; ++nt) acc[nt] = (v4f){0.f, 0.f, 0.f, 0.f};
        #pragma unroll
        for (int kc = 0; kc < 7; ++kc) {
            uint4 bu[7];
            #pragma unroll
            for (int nt = 0; nt < 7; ++nt) bu[nt] = FRAG_W1(nt * 7 + kc);
            const v8s af = mkfrag(xv[kc][0], xv[kc][1]);   // regs only
            #pragma unroll
            for (int nt = 0; nt < 7; ++nt)
                acc[nt] = mfma16(af, *(const v8s*)&bu[nt], acc[nt]);
        }

        // xv dead: issue NEXT tile's X loads; stream in under epi/L2/L3/GAS
        if (t < NTILES - 1) {
            #pragma unroll
            for (int kc = 0; kc < 7; ++kc) XLOADT(xv, gw0 + (t + 1) * 16, kc);
        }

        // epilogue -> slab (bf16 [16 rows][stride 264]); transient bias
        {
            float bv[7];
            #pragma unroll
            for (int nt = 0; nt < 7; ++nt) {
                const int c = nt * 16 + l15;
                bv[nt] = (c < 100) ? b1[c] : 0.f;
            }
            #pragma unroll
            for (int nt = 0; nt < 7; ++nt)
                #pragma unroll
                for (int r = 0; r < 4; ++r) {
                    const float v = fmaxf(acc[nt][r] + bv[nt], 0.f);
                    *(unsigned short*)(&L[sb_epi + r * SLAB_STRIDE + nt * 32]) =
                        f2bf(v);
                }
        }
        // zero cols 112..127 (100..111 zero via zero-padded frags)
        if (lane < 32)
            *(uint4*)(&L[sb + (lane >> 1) * SLAB_STRIDE + 224 + (lane & 1) * 16]) =
                make_uint4(0, 0, 0, 0);

        // ================= layer 2: h2 = relu(h1 @ W2 + b2) =============
        v4f acc2[7];
        #pragma unroll
        for (int nt = 0; nt < 7; ++nt) acc2[nt] = (v4f){0.f, 0.f, 0.f, 0.f};
        #pragma unroll
        for (int kc = 0; kc < 4; ++kc) {
            uint4 bu[7];
            #pragma unroll
            for (int nt = 0; nt < 7; ++nt) bu[nt] = FRAG_W2(nt * 4 + kc);
            uint4 t0 = *(const uint4*)(&L[sb_rd + kc * 64]);
            const v8s af = *(v8s*)&t0;
            #pragma unroll
            for (int nt = 0; nt < 7; ++nt)
                acc2[nt] = mfma16(af, *(const v8s*)&bu[nt], acc2[nt]);
        }
        // h2 overwrites h1 in-place (in-wave DS ordering); pads keep zeros
        {
            float bv[7];
            #pragma unroll
            for (int nt = 0; nt < 7; ++nt) {
                const int c = nt * 16 + l15;
                bv[nt] = (c < 100) ? b2[c] : 0.f;
            }
            #pragma unroll
            for (int nt = 0; nt < 7; ++nt)
                #pragma unroll
                for (int r = 0; r < 4; ++r) {
                    const float v = fmaxf(acc2[nt][r] + bv[nt], 0.f);
                    *(unsigned short*)(&L[sb_epi + r * SLAB_STRIDE + nt * 32]) =
                        f2bf(v);
                }
        }

        // ================= layer 3: DP = h2 @ W3 + b3 ===================
        v4f acc3[4];
        #pragma unroll
        for (int nt = 0; nt < 4; ++nt) acc3[nt] = (v4f){0.f, 0.f, 0.f, 0.f};
        #pragma unroll
        for (int kc = 0; kc < 4; ++kc) {
            uint4 bu[4];
            #pragma unroll
            for (int nt = 0; nt < 4; ++nt) bu[nt] = FRAG_W3(nt * 4 + kc);
            uint4 t0 = *(const uint4*)(&L[sb_rd + kc * 64]);
            const v8s af = *(v8s*)&t0;
            #pragma unroll
            for (int nt = 0; nt < 4; ++nt)
                acc3[nt] = mfma16(af, *(const v8s*)&bu[nt], acc3[nt]);
        }
        // DP (f32 [16][64]) overwrites slab (h2 reads precede in program order)
        {
            float bv[4];
            #pragma unroll
            for (int nt = 0; nt < 4; ++nt) bv[nt] = b3[nt * 16 + l15];
            #pragma unroll
            for (int nt = 0; nt < 4; ++nt)
                #pragma unroll
                for (int r = 0; r < 4; ++r)
                    *(float*)(&L[sb_dpw + r * SLAB_STRIDE + nt * 64]) =
                        acc3[nt][r] + bv[nt];
        }

        // ====== Student-t GAS recurrence: lane<16 owns one row ======
        if (lane < 16) {
            float mu = mu_init;
            float s2 = s2_init;
#define GAS_STEP(Y, O)                                                  \
            {   const float e    = (Y) - mu;                            \
                const float nus2 = anu * s2;                            \
                const float den  = fmaf(e, e, nus2);                    \
                const float r0   = __builtin_amdgcn_rcpf(den);          \
                const float p    = e * nus2 * r0;                       \
                mu = fmaf(cmu, p, fmaf(bMu, mu, oMu));                  \
                s2 = fmaf(cs, e * p, fmaf(bs2, s2, oSg));               \
                (O) = fmaf((Y), __builtin_amdgcn_sqrtf(s2), mu); }
            #pragma unroll
            for (int q = 0; q < 16; ++q) {
                float4 d = *(float4*)(&L[sb_gas + q * 16]);
                float o0, o1, o2, o3;
                GAS_STEP(d.x, o0); GAS_STEP(d.y, o1);
                GAS_STEP(d.z, o2); GAS_STEP(d.w, o3);
                *(float4*)(&L[sb_gas + q * 16]) = make_float4(o0, o1, o2, o3);
            }
#undef GAS_STEP
        }

        // ============ wave-wide coalesced float4 store (no barrier) =======
        if (active) {
            #pragma unroll
            for (int i = 0; i < 4; ++i) {
                float4 v = *(float4*)(&L[sb_st + i * (4 * SLAB_STRIDE)]);
                ((float4*)out)[gw * 16 + i * 64 + lane] = v;
            }
        }
    }
#undef FRAG_W1
#undef FRAG_W2
#undef FRAG_W3
#undef XLOADT
}

extern "C" void kernel_launch(void* const* d_in, const int* in_sizes, int n_in,
                              void* d_out, int out_size, void* d_ws, size_t ws_size,
                              hipStream_t stream) {
    const float* x          = (const float*)d_in[0];
    const float* last_mu    = (const float*)d_in[1];
    const float* last_sigma = (const float*)d_in[2];
    const float* amu        = (const float*)d_in[3];
    const float* asig       = (const float*)d_in[4];
    const float* bmu        = (const float*)d_in[5];
    const float* bsig       = (const float*)d_in[6];
    const float* omu        = (const float*)d_in[7];
    const float* osig       = (const float*)d_in[8];
    const float* nu         = (const float*)d_in[9];
    const float* ns         = (const float*)d_in[10];
    const float* W1         = (const float*)d_in[11];
    const float* b1         = (const float*)d_in[12];
    const float* W2         = (const float*)d_in[13];
    const float* b2         = (const float*)d_in[14];
    const float* W3         = (const float*)d_in[15];
    const float* b3         = (const float*)d_in[16];
    float* out = (float*)d_out;

    uint4* wf = (uint4*)d_ws;   // 95,232 B fragment table (93 frags)
    prep_weights<<<93, 64, 0, stream>>>(W1, W2, W3, wf);

    hipFuncSetAttribute((const void*)ar_gas_v20,
                        hipFuncAttributeMaxDynamicSharedMemorySize, LDS_TOTAL);

    dim3 grid((WTASKS + WAVES - 1) / WAVES), block(THREADS);   // 342 blocks
    ar_gas_v20<<<grid, block, LDS_TOTAL, stream>>>(
        x, last_mu, last_sigma,
        amu, asig, bmu, bsig, omu, osig, nu, ns,
        b1, b2, b3, wf, out);
}

// Round 21
// 88.222 us; speedup vs baseline: 1.4950x; 1.2130x over previous
//
#include <hip/hip_runtime.h>
#include <hip/hip_bf16.h>

typedef short v8s __attribute__((ext_vector_type(8)));
typedef float v4f __attribute__((ext_vector_type(4)));

#define THREADS 512      // 8 waves; each wave: 4 tiles x 16 rows = 64 rows
#define WAVES   8
#define NTILES  4
#define BMROWS  512      // rows per block
// d_ws frag order: W1 0-48, W2 49-76, W3 77-92 (slot s at LDS s*1024)
#define W1F     0
#define W2F     49
#define W3F     77
#define SLABB   95232                    // 93 frag slots end here
#define SLAB_STRIDE 264
#define SLAB_SIZE   4224                 // 16 rows * 264
#define LDS_TOTAL   (SLABB + WAVES * SLAB_SIZE)   // 129,024 B -> 1 block/CU

__device__ __forceinline__ unsigned short f2bf(float f) {
    union { __hip_bfloat16 h; unsigned short u; } c;
    c.h = __float2bfloat16(f);
    return c.u;
}
__device__ __forceinline__ unsigned pk2(float a, float b) {
    return (unsigned)f2bf(a) | ((unsigned)f2bf(b) << 16);
}
__device__ __forceinline__ v4f mfma16(v8s a, v8s b, v4f c) {
    return __builtin_amdgcn_mfma_f32_16x16x32_bf16(a, b, c, 0, 0, 0);
}
__device__ __forceinline__ v8s mkfrag(float4 a, float4 b) {
    union { unsigned u[4]; v8s s; } t;
    t.u[0] = pk2(a.x, a.y); t.u[1] = pk2(a.z, a.w);
    t.u[2] = pk2(b.x, b.y); t.u[3] = pk2(b.z, b.w);
    return t.s;
}
__device__ __forceinline__ void gload_lds16(const void* g, void* l) {
    __builtin_amdgcn_global_load_lds(
        (const __attribute__((address_space(1))) void*)g,
        (__attribute__((address_space(3))) void*)l, 16, 0, 0);
}

// ---- prep: weights -> MFMA B-fragment layout (bf16, zero-padded) ----------
// frag(nt,kc): lane l holds B[k = kc*32+(l>>4)*8+j][n = nt*16+(l&15)], j=0..7
__global__ void prep_weights(const float* __restrict__ W1,
                             const float* __restrict__ W2,
                             const float* __restrict__ W3,
                             uint4* __restrict__ wf) {
    const int bid = blockIdx.x, l = threadIdx.x;
    const float* W; int K, N, KC, base, f;
    if (bid < 49)      { W = W1; K = 200; N = 100; KC = 7; base = W1F * 64; f = bid; }
    else if (bid < 77) { W = W2; K = 100; N = 100; KC = 4; base = W2F * 64; f = bid - 49; }
    else               { W = W3; K = 100; N = 64;  KC = 4; base = W3F * 64; f = bid - 77; }
    const int kc = f % KC;
    const int n  = (f / KC) * 16 + (l & 15);
    unsigned u[4];
    #pragma unroll
    for (int p = 0; p < 4; ++p) {
        const int k0 = kc * 32 + (l >> 4) * 8 + p * 2;
        const float a = (k0     < K && n < N) ? W[(size_t)k0 * N + n]       : 0.f;
        const float b = (k0 + 1 < K && n < N) ? W[(size_t)(k0 + 1) * N + n] : 0.f;
        u[p] = pk2(a, b);
    }
    wf[base + f * 64 + l] = make_uint4(u[0], u[1], u[2], u[3]);
}

__global__ __launch_bounds__(THREADS, 2)   // cap 256: the only no-spill regime
void ar_gas_v21(const float* __restrict__ x,
                const float* __restrict__ last_mu,
                const float* __restrict__ last_sigma,
                const float* __restrict__ p_amu, const float* __restrict__ p_as,
                const float* __restrict__ p_bmu, const float* __restrict__ p_bs,
                const float* __restrict__ p_omu, const float* __restrict__ p_os,
                const float* __restrict__ p_nu,  const float* __restrict__ p_ns,
                const float* __restrict__ b1, const float* __restrict__ b2,
                const float* __restrict__ b3,
                const uint4* __restrict__ wf,
                float* __restrict__ out)
{
    extern __shared__ __align__(16) unsigned char L[];
    const int tid  = threadIdx.x;
    const int lane = tid & 63;
    const int wid  = tid >> 6;
    const int l15  = lane & 15;
    const int l4   = lane >> 4;
    const int blk  = blockIdx.x;

    // GAS scalars (uniform)
    const float anu = *p_nu,  ans = *p_ns;
    const float aMu = *p_amu, aSg = *p_as;
    const float bMu = *p_bmu, bSg = *p_bs;
    const float oMu = *p_omu, oSg = *p_os;
    const float wS  = 1.f + __builtin_amdgcn_rcpf(anu);
    const float cmu = ans * aMu * wS;
    const float cs  = ans * aSg * wS;
    const float bs2 = bSg - ans * aSg;

#define XLOADT(dst, base_row, kk)                                       \
    { int kb = (kk) * 32 + l4 * 8;                                      \
      kb = (kb + 8 <= 200) ? kb : 168;   /* clamp x zero-pad W1 = 0 */  \
      const float* p_ = x + ((base_row) + l15) * 200;                   \
      dst[kk][0] = *(const float4*)(p_ + kb);                           \
      dst[kk][1] = *(const float4*)(p_ + kb + 4); }

    // wave rows: [gw0, gw0+64), tile t rows gw0 + t*16
    const size_t gw0 = (size_t)blk * BMROWS + (size_t)wid * 64;

    // ---- prologue burst: X(tile0) into 56 VGPRs + all 93 frags -> LDS ----
    float4 xv[7][2];
    #pragma unroll
    for (int kc = 0; kc < 7; ++kc) XLOADT(xv, gw0, kc);

    for (int s = wid; s < 93; s += WAVES)
        gload_lds16(wf + s * 64 + lane, L + s * 1024);
    __syncthreads();   // THE only barrier

#define FRAG_W1(f)  (*(const uint4*)(&L[(W1F + (f)) * 1024 + lane * 16]))
#define FRAG_W2(f)  (*(const uint4*)(&L[(W2F + (f)) * 1024 + lane * 16]))
#define FRAG_W3(f)  (*(const uint4*)(&L[(W3F + (f)) * 1024 + lane * 16]))

    // affine slab bases (ds offsets compile-time)
    const int sb      = SLABB + wid * SLAB_SIZE;
    const int sb_epi  = sb + (l4 * 4) * SLAB_STRIDE + l15 * 2;  // +r*264+nt*32
    const int sb_rd   = sb + l15 * SLAB_STRIDE + l4 * 16;       // +kc*64
    const int sb_dpw  = sb + (l4 * 4) * SLAB_STRIDE + l15 * 4;  // +r*264+nt*64
    const int sb_gas  = sb + l15 * SLAB_STRIDE;                 // +q*16
    const int sb_st   = sb + l4 * SLAB_STRIDE + l15 * 16;       // +i*1056

    // cross-tile GAS pipeline state (tile t-1's recurrence runs inside
    // tile t's L1 MFMA loop; slab(t-1) holds its DP until epilogue(t))
    float  mu_g = 0.f, s2_g = 1.f;
    size_t gw_prev = 0;

#define GAS_STEP(Y, O)                                                  \
    {   const float e    = (Y) - mu_g;                                  \
        const float nus2 = anu * s2_g;                                  \
        const float den  = fmaf(e, e, nus2);                            \
        const float r0   = __builtin_amdgcn_rcpf(den);                  \
        const float p    = e * nus2 * r0;                               \
        mu_g = fmaf(cmu, p, fmaf(bMu, mu_g, oMu));                      \
        s2_g = fmaf(cs, e * p, fmaf(bs2, s2_g, oSg));                   \
        (O) = fmaf((Y), __builtin_amdgcn_sqrtf(s2_g), mu_g); }

#define GAS_Q(q)                                                        \
    if (doGas) {                                                        \
        float4 d = *(float4*)(&L[sb_gas + (q) * 16]);                   \
        float o0, o1, o2, o3;                                           \
        GAS_STEP(d.x, o0); GAS_STEP(d.y, o1);                           \
        GAS_STEP(d.z, o2); GAS_STEP(d.w, o3);                           \
        *(float4*)(&L[sb_gas + (q) * 16]) = make_float4(o0, o1, o2, o3);\
    }

    #pragma unroll 1
    for (int t = 0; t < NTILES; ++t) {
        const size_t gw = gw0 + t * 16;
        const bool doGas = (t > 0) && (lane < 16);

        // ====== layer 1 MFMA loop, with GAS(t-1) interleaved ======
        v4f acc[7];
        #pragma unroll
        for (int nt = 0; nt < 7; ++nt) acc[nt] = (v4f){0.f, 0.f, 0.f, 0.f};
        #pragma unroll
        for (int kc = 0; kc < 7; ++kc) {
            uint4 bu[7];
            #pragma unroll
            for (int nt = 0; nt < 7; ++nt) bu[nt] = FRAG_W1(nt * 7 + kc);
            const v8s af = mkfrag(xv[kc][0], xv[kc][1]);
            GAS_Q(2 * kc);          // 2 quad-steps of t-1's recurrence hide
            GAS_Q(2 * kc + 1);      // under this kc's 7 MFMAs + frag reads
            #pragma unroll
            for (int nt = 0; nt < 7; ++nt)
                acc[nt] = mfma16(af, *(const v8s*)&bu[nt], acc[nt]);
        }
        GAS_Q(14);
        GAS_Q(15);
        // store tile t-1's finished rows (slab reads precede epilogue writes)
        if (t > 0) {
            #pragma unroll
            for (int i = 0; i < 4; ++i) {
                float4 v = *(float4*)(&L[sb_st + i * (4 * SLAB_STRIDE)]);
                ((float4*)out)[gw_prev * 16 + i * 64 + lane] = v;
            }
        }

        // xv dead: next tile's X loads stream in under epi/L2/L3
        if (t < NTILES - 1) {
            #pragma unroll
            for (int kc = 0; kc < 7; ++kc) XLOADT(xv, gw + 16, kc);
        }

        // state for tile t's GAS (consumed during tile t+1 / tail)
        mu_g = last_mu[gw + l15];
        s2_g = last_sigma[gw + l15];
        gw_prev = gw;

        // epilogue -> slab (bf16 [16 rows][stride 264]); transient bias
        {
            float bv[7];
            #pragma unroll
            for (int nt = 0; nt < 7; ++nt) {
                const int c = nt * 16 + l15;
                bv[nt] = (c < 100) ? b1[c] : 0.f;
            }
            #pragma unroll
            for (int nt = 0; nt < 7; ++nt)
                #pragma unroll
                for (int r = 0; r < 4; ++r) {
                    const float v = fmaxf(acc[nt][r] + bv[nt], 0.f);
                    *(unsigned short*)(&L[sb_epi + r * SLAB_STRIDE + nt * 32]) =
                        f2bf(v);
                }
        }
        // zero cols 112..127 (100..111 zero via zero-padded frags)
        if (lane < 32)
            *(uint4*)(&L[sb + (lane >> 1) * SLAB_STRIDE + 224 + (lane & 1) * 16]) =
                make_uint4(0, 0, 0, 0);

        // ================= layer 2: h2 = relu(h1 @ W2 + b2) =============
        v4f acc2[7];
        #pragma unroll
        for (int nt = 0; nt < 7; ++nt) acc2[nt] = (v4f){0.f, 0.f, 0.f, 0.f};
        #pragma unroll
        for (int kc = 0; kc < 4; ++kc) {
            uint4 bu[7];
            #pragma unroll
            for (int nt = 0; nt < 7; ++nt) bu[nt] = FRAG_W2(nt * 4 + kc);
            uint4 t0 = *(const uint4*)(&L[sb_rd + kc * 64]);
            const v8s af = *(v8s*)&t0;
            #pragma unroll
            for (int nt = 0; nt < 7; ++nt)
                acc2[nt] = mfma16(af, *(const v8s*)&bu[nt], acc2[nt]);
        }
        {
            float bv[7];
            #pragma unroll
            for (int nt = 0; nt < 7; ++nt) {
                const int c = nt * 16 + l15;
                bv[nt] = (c < 100) ? b2[c] : 0.f;
            }
            #pragma unroll
            for (int nt = 0; nt < 7; ++nt)
                #pragma unroll
                for (int r = 0; r < 4; ++r) {
                    const float v = fmaxf(acc2[nt][r] + bv[nt], 0.f);
                    *(unsigned short*)(&L[sb_epi + r * SLAB_STRIDE + nt * 32]) =
                        f2bf(v);
                }
        }

        // ================= layer 3: DP = h2 @ W3 + b3 ===================
        v4f acc3[4];
        #pragma unroll
        for (int nt = 0; nt < 4; ++nt) acc3[nt] = (v4f){0.f, 0.f, 0.f, 0.f};
        #pragma unroll
        for (int kc = 0; kc < 4; ++kc) {
            uint4 bu[4];
            #pragma unroll
            for (int nt = 0; nt < 4; ++nt) bu[nt] = FRAG_W3(nt * 4 + kc);
            uint4 t0 = *(const uint4*)(&L[sb_rd + kc * 64]);
            const v8s af = *(v8s*)&t0;
            #pragma unroll
            for (int nt = 0; nt < 4; ++nt)
                acc3[nt] = mfma16(af, *(const v8s*)&bu[nt], acc3[nt]);
        }
        // DP (f32 [16][64]) -> slab (h2 reads precede in program order)
        {
            float bv[4];
            #pragma unroll
            for (int nt = 0; nt < 4; ++nt) bv[nt] = b3[nt * 16 + l15];
            #pragma unroll
            for (int nt = 0; nt < 4; ++nt)
                #pragma unroll
                for (int r = 0; r < 4; ++r)
                    *(float*)(&L[sb_dpw + r * SLAB_STRIDE + nt * 64]) =
                        acc3[nt][r] + bv[nt];
        }
    }

    // ====== tail: GAS + store for the last tile (runs bare once) ======
    {
        const bool doGas = (lane < 16);
        #pragma unroll
        for (int q = 0; q < 16; ++q) { GAS_Q(q); }
        #pragma unroll
        for (int i = 0; i < 4; ++i) {
            float4 v = *(float4*)(&L[sb_st + i * (4 * SLAB_STRIDE)]);
            ((float4*)out)[gw_prev * 16 + i * 64 + lane] = v;
        }
    }
#undef GAS_Q
#undef GAS_STEP
#undef FRAG_W1
#undef FRAG_W2
#undef FRAG_W3
#undef XLOADT
}

extern "C" void kernel_launch(void* const* d_in, const int* in_sizes, int n_in,
                              void* d_out, int out_size, void* d_ws, size_t ws_size,
                              hipStream_t stream) {
    const float* x          = (const float*)d_in[0];
    const float* last_mu    = (const float*)d_in[1];
    const float* last_sigma = (const float*)d_in[2];
    const float* amu        = (const float*)d_in[3];
    const float* asig       = (const float*)d_in[4];
    const float* bmu        = (const float*)d_in[5];
    const float* bsig       = (const float*)d_in[6];
    const float* omu        = (const float*)d_in[7];
    const float* osig       = (const float*)d_in[8];
    const float* nu         = (const float*)d_in[9];
    const float* ns         = (const float*)d_in[10];
    const float* W1         = (const float*)d_in[11];
    const float* b1         = (const float*)d_in[12];
    const float* W2         = (const float*)d_in[13];
    const float* b2         = (const float*)d_in[14];
    const float* W3         = (const float*)d_in[15];
    const float* b3         = (const float*)d_in[16];
    float* out = (float*)d_out;

    uint4* wf = (uint4*)d_ws;   // 95,232 B fragment table (93 frags)
    prep_weights<<<93, 64, 0, stream>>>(W1, W2, W3, wf);

    hipFuncSetAttribute((const void*)ar_gas_v21,
                        hipFuncAttributeMaxDynamicSharedMemorySize, LDS_TOTAL);

    const int B = in_sizes[1];                 // 262144
    dim3 grid(B / BMROWS), block(THREADS);     // 512 blocks x 512 threads
    ar_gas_v21<<<grid, block, LDS_TOTAL, stream>>>(
        x, last_mu, last_sigma,
        amu, asig, bmu, bsig, omu, osig, nu, ns,
        b1, b2, b3, wf, out);
}

// Round 22
// 81.959 us; speedup vs baseline: 1.6092x; 1.0764x over previous
//
#include <hip/hip_runtime.h>
#include <hip/hip_bf16.h>

typedef short v8s __attribute__((ext_vector_type(8)));
typedef float v4f __attribute__((ext_vector_type(4)));

#define THREADS 512      // 8 waves; each wave: 4 tiles x 16 rows = 64 rows
#define WAVES   8
#define NTILES  4
#define BMROWS  512      // rows per block
// d_ws frag order: W1 0-48, W2 49-76, W3 77-92 (slot s at LDS s*1024)
#define W1F     0
#define W2F     49
#define W3F     77
#define SLABB   95232                    // 93 frag slots end here
#define SLAB_STRIDE 264
#define SLAB_SIZE   4224                 // 16 rows * 264
#define LDS_TOTAL   (SLABB + WAVES * SLAB_SIZE)   // 129,024 B -> 1 block/CU

__device__ __forceinline__ unsigned short f2bf(float f) {
    union { __hip_bfloat16 h; unsigned short u; } c;
    c.h = __float2bfloat16(f);
    return c.u;
}
__device__ __forceinline__ unsigned pk2(float a, float b) {
    return (unsigned)f2bf(a) | ((unsigned)f2bf(b) << 16);
}
__device__ __forceinline__ v4f mfma16(v8s a, v8s b, v4f c) {
    return __builtin_amdgcn_mfma_f32_16x16x32_bf16(a, b, c, 0, 0, 0);
}
__device__ __forceinline__ v8s mkfrag(float4 a, float4 b) {
    union { unsigned u[4]; v8s s; } t;
    t.u[0] = pk2(a.x, a.y); t.u[1] = pk2(a.z, a.w);
    t.u[2] = pk2(b.x, b.y); t.u[3] = pk2(b.z, b.w);
    return t.s;
}
__device__ __forceinline__ void gload_lds16(const void* g, void* l) {
    __builtin_amdgcn_global_load_lds(
        (const __attribute__((address_space(1))) void*)g,
        (__attribute__((address_space(3))) void*)l, 16, 0, 0);
}

// ---- prep: weights -> MFMA B-fragment layout (bf16, zero-padded) ----------
// frag(nt,kc): lane l holds B[k = kc*32+(l>>4)*8+j][n = nt*16+(l&15)], j=0..7
__global__ void prep_weights(const float* __restrict__ W1,
                             const float* __restrict__ W2,
                             const float* __restrict__ W3,
                             uint4* __restrict__ wf) {
    const int bid = blockIdx.x, l = threadIdx.x;
    const float* W; int K, N, KC, base, f;
    if (bid < 49)      { W = W1; K = 200; N = 100; KC = 7; base = W1F * 64; f = bid; }
    else if (bid < 77) { W = W2; K = 100; N = 100; KC = 4; base = W2F * 64; f = bid - 49; }
    else               { W = W3; K = 100; N = 64;  KC = 4; base = W3F * 64; f = bid - 77; }
    const int kc = f % KC;
    const int n  = (f / KC) * 16 + (l & 15);
    unsigned u[4];
    #pragma unroll
    for (int p = 0; p < 4; ++p) {
        const int k0 = kc * 32 + (l >> 4) * 8 + p * 2;
        const float a = (k0     < K && n < N) ? W[(size_t)k0 * N + n]       : 0.f;
        const float b = (k0 + 1 < K && n < N) ? W[(size_t)(k0 + 1) * N + n] : 0.f;
        u[p] = pk2(a, b);
    }
    wf[base + f * 64 + l] = make_uint4(u[0], u[1], u[2], u[3]);
}

__global__ __launch_bounds__(THREADS, 2)   // cap 256: the only no-spill regime
void ar_gas_v22(const float* __restrict__ x,
                const float* __restrict__ last_mu,
                const float* __restrict__ last_sigma,
                const float* __restrict__ p_amu, const float* __restrict__ p_as,
                const float* __restrict__ p_bmu, const float* __restrict__ p_bs,
                const float* __restrict__ p_omu, const float* __restrict__ p_os,
                const float* __restrict__ p_nu,  const float* __restrict__ p_ns,
                const float* __restrict__ b1, const float* __restrict__ b2,
                const float* __restrict__ b3,
                const uint4* __restrict__ wf,
                float* __restrict__ out)
{
    extern __shared__ __align__(16) unsigned char L[];
    const int tid  = threadIdx.x;
    const int lane = tid & 63;
    const int wid  = tid >> 6;
    const int l15  = lane & 15;
    const int l4   = lane >> 4;
    const int blk  = blockIdx.x;

    // GAS scalars (uniform)
    const float anu = *p_nu,  ans = *p_ns;
    const float aMu = *p_amu, aSg = *p_as;
    const float bMu = *p_bmu, bSg = *p_bs;
    const float oMu = *p_omu, oSg = *p_os;
    const float wS  = 1.f + __builtin_amdgcn_rcpf(anu);
    const float cmu = ans * aMu * wS;
    const float cs  = ans * aSg * wS;
    const float bs2 = bSg - ans * aSg;

#define XLOADT(dst, base_row, kk)                                       \
    { int kb = (kk) * 32 + l4 * 8;                                      \
      kb = (kb + 8 <= 200) ? kb : 168;   /* clamp x zero-pad W1 = 0 */  \
      const float* p_ = x + ((base_row) + l15) * 200;                   \
      dst[kk][0] = *(const float4*)(p_ + kb);                           \
      dst[kk][1] = *(const float4*)(p_ + kb + 4); }

    // wave rows: [gw0, gw0+64), tile t rows gw0 + t*16
    const size_t gw0 = (size_t)blk * BMROWS + (size_t)wid * 64;

    // ---- prologue burst: X(tile0) into 56 VGPRs + all 93 frags -> LDS ----
    float4 xv[7][2];
    #pragma unroll
    for (int kc = 0; kc < 7; ++kc) XLOADT(xv, gw0, kc);

    for (int s = wid; s < 93; s += WAVES)
        gload_lds16(wf + s * 64 + lane, L + s * 1024);
    __syncthreads();   // THE only barrier: X in regs, all frags resident

    // ---- wave-gradient phase stagger (de-phase SIMD siblings) ----
    // Waves are phase-locked after the barrier: both waves on a SIMD hit
    // the latency-bound GAS chain simultaneously -> dead SIMD time. A
    // ~450-cyc-per-wid sleep gradient offsets any sibling pair by >=450
    // cyc (w,w+4 mapping: ~1.8K), so one wave's GAS overlaps the other's
    // MFMA/LDS phases for the rest of the kernel.
    for (int i = 0; i < wid; ++i) __builtin_amdgcn_s_sleep(7);

#define FRAG_W1(f)  (*(const uint4*)(&L[(W1F + (f)) * 1024 + lane * 16]))
#define FRAG_W2(f)  (*(const uint4*)(&L[(W2F + (f)) * 1024 + lane * 16]))
#define FRAG_W3(f)  (*(const uint4*)(&L[(W3F + (f)) * 1024 + lane * 16]))

    // affine slab bases (all ds offsets are compile-time constants)
    const int sb      = SLABB + wid * SLAB_SIZE;
    const int sb_epi  = sb + (l4 * 4) * SLAB_STRIDE + l15 * 2;  // +r*264+nt*32
    const int sb_rd   = sb + l15 * SLAB_STRIDE + l4 * 16;       // +kc*64
    const int sb_dpw  = sb + (l4 * 4) * SLAB_STRIDE + l15 * 4;  // +r*264+nt*64
    const int sb_gas  = sb + l15 * SLAB_STRIDE;                 // +q*16
    const int sb_st   = sb + l4 * SLAB_STRIDE + l15 * 16;       // +i*1056

    #pragma unroll 1
    for (int t = 0; t < NTILES; ++t) {
        const size_t gw = gw0 + t * 16;

        // state loads now; consumed at GAS ~6K cyc later
        const float mu_init = last_mu[gw + l15];
        const float s2_init = last_sigma[gw + l15];

        // ================= layer 1: h1 = relu(X @ W1 + b1) ==============
        v4f acc[7];
        #pragma unroll
        for (int nt = 0; nt < 7; ++nt) acc[nt] = (v4f){0.f, 0.f, 0.f, 0.f};
        #pragma unroll
        for (int kc = 0; kc < 7; ++kc) {
            uint4 bu[7];
            #pragma unroll
            for (int nt = 0; nt < 7; ++nt) bu[nt] = FRAG_W1(nt * 7 + kc);
            const v8s af = mkfrag(xv[kc][0], xv[kc][1]);   // regs only
            #pragma unroll
            for (int nt = 0; nt < 7; ++nt)
                acc[nt] = mfma16(af, *(const v8s*)&bu[nt], acc[nt]);
        }

        // xv dead: issue NEXT tile's X loads; stream in under epi/L2/L3/GAS
        if (t < NTILES - 1) {
            #pragma unroll
            for (int kc = 0; kc < 7; ++kc) XLOADT(xv, gw0 + (t + 1) * 16, kc);
        }

        // epilogue -> slab (bf16 [16 rows][stride 264]); transient bias
        {
            float bv[7];
            #pragma unroll
            for (int nt = 0; nt < 7; ++nt) {
                const int c = nt * 16 + l15;
                bv[nt] = (c < 100) ? b1[c] : 0.f;
            }
            #pragma unroll
            for (int nt = 0; nt < 7; ++nt)
                #pragma unroll
                for (int r = 0; r < 4; ++r) {
                    const float v = fmaxf(acc[nt][r] + bv[nt], 0.f);
                    *(unsigned short*)(&L[sb_epi + r * SLAB_STRIDE + nt * 32]) =
                        f2bf(v);
                }
        }
        // zero cols 112..127 (100..111 zero via zero-padded frags)
        if (lane < 32)
            *(uint4*)(&L[sb + (lane >> 1) * SLAB_STRIDE + 224 + (lane & 1) * 16]) =
                make_uint4(0, 0, 0, 0);

        // ================= layer 2: h2 = relu(h1 @ W2 + b2) =============
        v4f acc2[7];
        #pragma unroll
        for (int nt = 0; nt < 7; ++nt) acc2[nt] = (v4f){0.f, 0.f, 0.f, 0.f};
        #pragma unroll
        for (int kc = 0; kc < 4; ++kc) {
            uint4 bu[7];
            #pragma unroll
            for (int nt = 0; nt < 7; ++nt) bu[nt] = FRAG_W2(nt * 4 + kc);
            uint4 t0 = *(const uint4*)(&L[sb_rd + kc * 64]);
            const v8s af = *(v8s*)&t0;
            #pragma unroll
            for (int nt = 0; nt < 7; ++nt)
                acc2[nt] = mfma16(af, *(const v8s*)&bu[nt], acc2[nt]);
        }
        // h2 overwrites h1 in-place (in-wave DS ordering); pads keep zeros
        {
            float bv[7];
            #pragma unroll
            for (int nt = 0; nt < 7; ++nt) {
                const int c = nt * 16 + l15;
                bv[nt] = (c < 100) ? b2[c] : 0.f;
            }
            #pragma unroll
            for (int nt = 0; nt < 7; ++nt)
                #pragma unroll
                for (int r = 0; r < 4; ++r) {
                    const float v = fmaxf(acc2[nt][r] + bv[nt], 0.f);
                    *(unsigned short*)(&L[sb_epi + r * SLAB_STRIDE + nt * 32]) =
                        f2bf(v);
                }
        }

        // ================= layer 3: DP = h2 @ W3 + b3 ===================
        v4f acc3[4];
        #pragma unroll
        for (int nt = 0; nt < 4; ++nt) acc3[nt] = (v4f){0.f, 0.f, 0.f, 0.f};
        #pragma unroll
        for (int kc = 0; kc < 4; ++kc) {
            uint4 bu[4];
            #pragma unroll
            for (int nt = 0; nt < 4; ++nt) bu[nt] = FRAG_W3(nt * 4 + kc);
            uint4 t0 = *(const uint4*)(&L[sb_rd + kc * 64]);
            const v8s af = *(v8s*)&t0;
            #pragma unroll
            for (int nt = 0; nt < 4; ++nt)
                acc3[nt] = mfma16(af, *(const v8s*)&bu[nt], acc3[nt]);
        }
        // DP (f32 [16][64]) overwrites slab (h2 reads precede in program order)
        {
            float bv[4];
            #pragma unroll
            for (int nt = 0; nt < 4; ++nt) bv[nt] = b3[nt * 16 + l15];
            #pragma unroll
            for (int nt = 0; nt < 4; ++nt)
                #pragma unroll
                for (int r = 0; r < 4; ++r)
                    *(float*)(&L[sb_dpw + r * SLAB_STRIDE + nt * 64]) =
                        acc3[nt][r] + bv[nt];
        }

        // ====== Student-t GAS recurrence: lane<16 owns one row ======
        if (lane < 16) {
            float mu = mu_init;
            float s2 = s2_init;
#define GAS_STEP(Y, O)                                                  \
            {   const float e    = (Y) - mu;                            \
                const float nus2 = anu * s2;                            \
                const float den  = fmaf(e, e, nus2);                    \
                const float r0   = __builtin_amdgcn_rcpf(den);          \
                const float p    = e * nus2 * r0;                       \
                mu = fmaf(cmu, p, fmaf(bMu, mu, oMu));                  \
                s2 = fmaf(cs, e * p, fmaf(bs2, s2, oSg));               \
                (O) = fmaf((Y), __builtin_amdgcn_sqrtf(s2), mu); }
            #pragma unroll
            for (int q = 0; q < 16; ++q) {
                float4 d = *(float4*)(&L[sb_gas + q * 16]);
                float o0, o1, o2, o3;
                GAS_STEP(d.x, o0); GAS_STEP(d.y, o1);
                GAS_STEP(d.z, o2); GAS_STEP(d.w, o3);
                *(float4*)(&L[sb_gas + q * 16]) = make_float4(o0, o1, o2, o3);
            }
#undef GAS_STEP
        }

        // ============ wave-wide coalesced float4 store (no barrier) =======
        #pragma unroll
        for (int i = 0; i < 4; ++i) {
            float4 v = *(float4*)(&L[sb_st + i * (4 * SLAB_STRIDE)]);
            ((float4*)out)[gw * 16 + i * 64 + lane] = v;
        }
    }
#undef FRAG_W1
#undef FRAG_W2
#undef FRAG_W3
#undef XLOADT
}

extern "C" void kernel_launch(void* const* d_in, const int* in_sizes, int n_in,
                              void* d_out, int out_size, void* d_ws, size_t ws_size,
                              hipStream_t stream) {
    const float* x          = (const float*)d_in[0];
    const float* last_mu    = (const float*)d_in[1];
    const float* last_sigma = (const float*)d_in[2];
    const float* amu        = (const float*)d_in[3];
    const float* asig       = (const float*)d_in[4];
    const float* bmu        = (const float*)d_in[5];
    const float* bsig       = (const float*)d_in[6];
    const float* omu        = (const float*)d_in[7];
    const float* osig       = (const float*)d_in[8];
    const float* nu         = (const float*)d_in[9];
    const float* ns         = (const float*)d_in[10];
    const float* W1         = (const float*)d_in[11];
    const float* b1         = (const float*)d_in[12];
    const float* W2         = (const float*)d_in[13];
    const float* b2         = (const float*)d_in[14];
    const float* W3         = (const float*)d_in[15];
    const float* b3         = (const float*)d_in[16];
    float* out = (float*)d_out;

    uint4* wf = (uint4*)d_ws;   // 95,232 B fragment table (93 frags)
    prep_weights<<<93, 64, 0, stream>>>(W1, W2, W3, wf);

    hipFuncSetAttribute((const void*)ar_gas_v22,
                        hipFuncAttributeMaxDynamicSharedMemorySize, LDS_TOTAL);

    const int B = in_sizes[1];                 // 262144
    dim3 grid(B / BMROWS), block(THREADS);     // 512 blocks x 512 threads
    ar_gas_v22<<<grid, block, LDS_TOTAL, stream>>>(
        x, last_mu, last_sigma,
        amu, asig, bmu, bsig, omu, osig, nu, ns,
        b1, b2, b3, wf, out);
}

// Round 23
// 75.804 us; speedup vs baseline: 1.7398x; 1.0812x over previous
//
#include <hip/hip_runtime.h>
#include <hip/hip_bf16.h>

typedef short v8s __attribute__((ext_vector_type(8)));
typedef float v4f __attribute__((ext_vector_type(4)));

#define THREADS 512      // 8 waves; each wave: 8 tiles x 16 rows = 128 rows
#define WAVES   8
#define NTILES  8
#define BMROWS  1024     // rows per block -> grid = 256 = exactly 1 block/CU
// d_ws frag order: W1 0-48, W2 49-76, W3 77-92 (slot s at LDS s*1024)
#define W1F     0
#define W2F     49
#define W3F     77
#define SLABB   95232                    // 93 frag slots end here
#define SLAB_STRIDE 264
#define SLAB_SIZE   4224                 // 16 rows * 264
#define LDS_TOTAL   (SLABB + WAVES * SLAB_SIZE)   // 129,024 B -> 1 block/CU

__device__ __forceinline__ unsigned short f2bf(float f) {
    union { __hip_bfloat16 h; unsigned short u; } c;
    c.h = __float2bfloat16(f);
    return c.u;
}
__device__ __forceinline__ unsigned pk2(float a, float b) {
    return (unsigned)f2bf(a) | ((unsigned)f2bf(b) << 16);
}
__device__ __forceinline__ v4f mfma16(v8s a, v8s b, v4f c) {
    return __builtin_amdgcn_mfma_f32_16x16x32_bf16(a, b, c, 0, 0, 0);
}
__device__ __forceinline__ v8s mkfrag(float4 a, float4 b) {
    union { unsigned u[4]; v8s s; } t;
    t.u[0] = pk2(a.x, a.y); t.u[1] = pk2(a.z, a.w);
    t.u[2] = pk2(b.x, b.y); t.u[3] = pk2(b.z, b.w);
    return t.s;
}
__device__ __forceinline__ void gload_lds16(const void* g, void* l) {
    __builtin_amdgcn_global_load_lds(
        (const __attribute__((address_space(1))) void*)g,
        (__attribute__((address_space(3))) void*)l, 16, 0, 0);
}

// ---- prep: weights -> MFMA B-fragment layout (bf16, zero-padded) ----------
// frag(nt,kc): lane l holds B[k = kc*32+(l>>4)*8+j][n = nt*16+(l&15)], j=0..7
__global__ void prep_weights(const float* __restrict__ W1,
                             const float* __restrict__ W2,
                             const float* __restrict__ W3,
                             uint4* __restrict__ wf) {
    const int bid = blockIdx.x, l = threadIdx.x;
    const float* W; int K, N, KC, base, f;
    if (bid < 49)      { W = W1; K = 200; N = 100; KC = 7; base = W1F * 64; f = bid; }
    else if (bid < 77) { W = W2; K = 100; N = 100; KC = 4; base = W2F * 64; f = bid - 49; }
    else               { W = W3; K = 100; N = 64;  KC = 4; base = W3F * 64; f = bid - 77; }
    const int kc = f % KC;
    const int n  = (f / KC) * 16 + (l & 15);
    unsigned u[4];
    #pragma unroll
    for (int p = 0; p < 4; ++p) {
        const int k0 = kc * 32 + (l >> 4) * 8 + p * 2;
        const float a = (k0     < K && n < N) ? W[(size_t)k0 * N + n]       : 0.f;
        const float b = (k0 + 1 < K && n < N) ? W[(size_t)(k0 + 1) * N + n] : 0.f;
        u[p] = pk2(a, b);
    }
    wf[base + f * 64 + l] = make_uint4(u[0], u[1], u[2], u[3]);
}

__global__ __launch_bounds__(THREADS, 2)   // cap 256: the only no-spill regime
void ar_gas_v23(const float* __restrict__ x,
                const float* __restrict__ last_mu,
                const float* __restrict__ last_sigma,
                const float* __restrict__ p_amu, const float* __restrict__ p_as,
                const float* __restrict__ p_bmu, const float* __restrict__ p_bs,
                const float* __restrict__ p_omu, const float* __restrict__ p_os,
                const float* __restrict__ p_nu,  const float* __restrict__ p_ns,
                const float* __restrict__ b1, const float* __restrict__ b2,
                const float* __restrict__ b3,
                const uint4* __restrict__ wf,
                float* __restrict__ out)
{
    extern __shared__ __align__(16) unsigned char L[];
    const int tid  = threadIdx.x;
    const int lane = tid & 63;
    const int wid  = tid >> 6;
    const int l15  = lane & 15;
    const int l4   = lane >> 4;
    const int blk  = blockIdx.x;

    // GAS scalars (uniform)
    const float anu = *p_nu,  ans = *p_ns;
    const float aMu = *p_amu, aSg = *p_as;
    const float bMu = *p_bmu, bSg = *p_bs;
    const float oMu = *p_omu, oSg = *p_os;
    const float wS  = 1.f + __builtin_amdgcn_rcpf(anu);
    const float cmu = ans * aMu * wS;
    const float cs  = ans * aSg * wS;
    const float bs2 = bSg - ans * aSg;

#define XLOADT(dst, base_row, kk)                                       \
    { int kb = (kk) * 32 + l4 * 8;                                      \
      kb = (kb + 8 <= 200) ? kb : 168;   /* clamp x zero-pad W1 = 0 */  \
      const float* p_ = x + ((base_row) + l15) * 200;                   \
      dst[kk][0] = *(const float4*)(p_ + kb);                           \
      dst[kk][1] = *(const float4*)(p_ + kb + 4); }

    // wave rows: [gw0, gw0+128), tile t rows gw0 + t*16
    const size_t gw0 = (size_t)blk * BMROWS + (size_t)wid * (16 * NTILES);

    // ---- prologue burst: X(tile0) into 56 VGPRs + all 93 frags -> LDS ----
    float4 xv[7][2];
    #pragma unroll
    for (int kc = 0; kc < 7; ++kc) XLOADT(xv, gw0, kc);

    for (int s = wid; s < 93; s += WAVES)
        gload_lds16(wf + s * 64 + lane, L + s * 1024);
    __syncthreads();   // THE only barrier: X in regs, all frags resident

    // ---- wave-gradient phase stagger (de-phase SIMD siblings; r22 +1.6%) ----
    for (int i = 0; i < wid; ++i) __builtin_amdgcn_s_sleep(7);

#define FRAG_W1(f)  (*(const uint4*)(&L[(W1F + (f)) * 1024 + lane * 16]))
#define FRAG_W2(f)  (*(const uint4*)(&L[(W2F + (f)) * 1024 + lane * 16]))
#define FRAG_W3(f)  (*(const uint4*)(&L[(W3F + (f)) * 1024 + lane * 16]))

    // affine slab bases (all ds offsets are compile-time constants)
    const int sb      = SLABB + wid * SLAB_SIZE;
    const int sb_epi  = sb + (l4 * 4) * SLAB_STRIDE + l15 * 2;  // +r*264+nt*32
    const int sb_rd   = sb + l15 * SLAB_STRIDE + l4 * 16;       // +kc*64
    const int sb_dpw  = sb + (l4 * 4) * SLAB_STRIDE + l15 * 4;  // +r*264+nt*64
    const int sb_gas  = sb + l15 * SLAB_STRIDE;                 // +q*16
    const int sb_st   = sb + l4 * SLAB_STRIDE + l15 * 16;       // +i*1056

    #pragma unroll 1
    for (int t = 0; t < NTILES; ++t) {
        const size_t gw = gw0 + t * 16;

        // state loads now; consumed at GAS ~6K cyc later
        const float mu_init = last_mu[gw + l15];
        const float s2_init = last_sigma[gw + l15];

        // ================= layer 1: h1 = relu(X @ W1 + b1) ==============
        v4f acc[7];
        #pragma unroll
        for (int nt = 0; nt < 7; ++nt) acc[nt] = (v4f){0.f, 0.f, 0.f, 0.f};
        #pragma unroll
        for (int kc = 0; kc < 7; ++kc) {
            uint4 bu[7];
            #pragma unroll
            for (int nt = 0; nt < 7; ++nt) bu[nt] = FRAG_W1(nt * 7 + kc);
            const v8s af = mkfrag(xv[kc][0], xv[kc][1]);   // regs only
            #pragma unroll
            for (int nt = 0; nt < 7; ++nt)
                acc[nt] = mfma16(af, *(const v8s*)&bu[nt], acc[nt]);
        }

        // xv dead: issue NEXT tile's X loads; stream in under epi/L2/L3/GAS
        if (t < NTILES - 1) {
            #pragma unroll
            for (int kc = 0; kc < 7; ++kc) XLOADT(xv, gw0 + (t + 1) * 16, kc);
        }

        // epilogue -> slab (bf16 [16 rows][stride 264]); transient bias
        {
            float bv[7];
            #pragma unroll
            for (int nt = 0; nt < 7; ++nt) {
                const int c = nt * 16 + l15;
                bv[nt] = (c < 100) ? b1[c] : 0.f;
            }
            #pragma unroll
            for (int nt = 0; nt < 7; ++nt)
                #pragma unroll
                for (int r = 0; r < 4; ++r) {
                    const float v = fmaxf(acc[nt][r] + bv[nt], 0.f);
                    *(unsigned short*)(&L[sb_epi + r * SLAB_STRIDE + nt * 32]) =
                        f2bf(v);
                }
        }
        // zero cols 112..127 (100..111 zero via zero-padded frags)
        if (lane < 32)
            *(uint4*)(&L[sb + (lane >> 1) * SLAB_STRIDE + 224 + (lane & 1) * 16]) =
                make_uint4(0, 0, 0, 0);

        // ================= layer 2: h2 = relu(h1 @ W2 + b2) =============
        v4f acc2[7];
        #pragma unroll
        for (int nt = 0; nt < 7; ++nt) acc2[nt] = (v4f){0.f, 0.f, 0.f, 0.f};
        #pragma unroll
        for (int kc = 0; kc < 4; ++kc) {
            uint4 bu[7];
            #pragma unroll
            for (int nt = 0; nt < 7; ++nt) bu[nt] = FRAG_W2(nt * 4 + kc);
            uint4 t0 = *(const uint4*)(&L[sb_rd + kc * 64]);
            const v8s af = *(v8s*)&t0;
            #pragma unroll
            for (int nt = 0; nt < 7; ++nt)
                acc2[nt] = mfma16(af, *(const v8s*)&bu[nt], acc2[nt]);
        }
        // h2 overwrites h1 in-place (in-wave DS ordering); pads keep zeros
        {
            float bv[7];
            #pragma unroll
            for (int nt = 0; nt < 7; ++nt) {
                const int c = nt * 16 + l15;
                bv[nt] = (c < 100) ? b2[c] : 0.f;
            }
            #pragma unroll
            for (int nt = 0; nt < 7; ++nt)
                #pragma unroll
                for (int r = 0; r < 4; ++r) {
                    const float v = fmaxf(acc2[nt][r] + bv[nt], 0.f);
                    *(unsigned short*)(&L[sb_epi + r * SLAB_STRIDE + nt * 32]) =
                        f2bf(v);
                }
        }

        // ================= layer 3: DP = h2 @ W3 + b3 ===================
        v4f acc3[4];
        #pragma unroll
        for (int nt = 0; nt < 4; ++nt) acc3[nt] = (v4f){0.f, 0.f, 0.f, 0.f};
        #pragma unroll
        for (int kc = 0; kc < 4; ++kc) {
            uint4 bu[4];
            #pragma unroll
            for (int nt = 0; nt < 4; ++nt) bu[nt] = FRAG_W3(nt * 4 + kc);
            uint4 t0 = *(const uint4*)(&L[sb_rd + kc * 64]);
            const v8s af = *(v8s*)&t0;
            #pragma unroll
            for (int nt = 0; nt < 4; ++nt)
                acc3[nt] = mfma16(af, *(const v8s*)&bu[nt], acc3[nt]);
        }
        // DP (f32 [16][64]) overwrites slab (h2 reads precede in program order)
        {
            float bv[4];
            #pragma unroll
            for (int nt = 0; nt < 4; ++nt) bv[nt] = b3[nt * 16 + l15];
            #pragma unroll
            for (int nt = 0; nt < 4; ++nt)
                #pragma unroll
                for (int r = 0; r < 4; ++r)
                    *(float*)(&L[sb_dpw + r * SLAB_STRIDE + nt * 64]) =
                        acc3[nt][r] + bv[nt];
        }

        // ====== Student-t GAS recurrence: lane<16 owns one row ======
        if (lane < 16) {
            float mu = mu_init;
            float s2 = s2_init;
#define GAS_STEP(Y, O)                                                  \
            {   const float e    = (Y) - mu;                            \
                const float nus2 = anu * s2;                            \
                const float den  = fmaf(e, e, nus2);                    \
                const float r0   = __builtin_amdgcn_rcpf(den);          \
                const float p    = e * nus2 * r0;                       \
                mu = fmaf(cmu, p, fmaf(bMu, mu, oMu));                  \
                s2 = fmaf(cs, e * p, fmaf(bs2, s2, oSg));               \
                (O) = fmaf((Y), __builtin_amdgcn_sqrtf(s2), mu); }
            #pragma unroll
            for (int q = 0; q < 16; ++q) {
                float4 d = *(float4*)(&L[sb_gas + q * 16]);
                float o0, o1, o2, o3;
                GAS_STEP(d.x, o0); GAS_STEP(d.y, o1);
                GAS_STEP(d.z, o2); GAS_STEP(d.w, o3);
                *(float4*)(&L[sb_gas + q * 16]) = make_float4(o0, o1, o2, o3);
            }
#undef GAS_STEP
        }

        // ============ wave-wide coalesced float4 store (no barrier) =======
        #pragma unroll
        for (int i = 0; i < 4; ++i) {
            float4 v = *(float4*)(&L[sb_st + i * (4 * SLAB_STRIDE)]);
            ((float4*)out)[gw * 16 + i * 64 + lane] = v;
        }
    }
#undef FRAG_W1
#undef FRAG_W2
#undef FRAG_W3
#undef XLOADT
}

extern "C" void kernel_launch(void* const* d_in, const int* in_sizes, int n_in,
                              void* d_out, int out_size, void* d_ws, size_t ws_size,
                              hipStream_t stream) {
    const float* x          = (const float*)d_in[0];
    const float* last_mu    = (const float*)d_in[1];
    const float* last_sigma = (const float*)d_in[2];
    const float* amu        = (const float*)d_in[3];
    const float* asig       = (const float*)d_in[4];
    const float* bmu        = (const float*)d_in[5];
    const float* bsig       = (const float*)d_in[6];
    const float* omu        = (const float*)d_in[7];
    const float* osig       = (const float*)d_in[8];
    const float* nu         = (const float*)d_in[9];
    const float* ns         = (const float*)d_in[10];
    const float* W1         = (const float*)d_in[11];
    const float* b1         = (const float*)d_in[12];
    const float* W2         = (const float*)d_in[13];
    const float* b2         = (const float*)d_in[14];
    const float* W3         = (const float*)d_in[15];
    const float* b3         = (const float*)d_in[16];
    float* out = (float*)d_out;

    uint4* wf = (uint4*)d_ws;   // 95,232 B fragment table (93 frags)
    prep_weights<<<93, 64, 0, stream>>>(W1, W2, W3, wf);

    hipFuncSetAttribute((const void*)ar_gas_v23,
                        hipFuncAttributeMaxDynamicSharedMemorySize, LDS_TOTAL);

    const int B = in_sizes[1];                 // 262144
    dim3 grid(B / BMROWS), block(THREADS);     // 256 blocks = 1 per CU
    ar_gas_v23<<<grid, block, LDS_TOTAL, stream>>>(
        x, last_mu, last_sigma,
        amu, asig, bmu, bsig, omu, osig, nu, ns,
        b1, b2, b3, wf, out);
}